// Round 2
// baseline (10345.678 us; speedup 1.0000x reference)
//
#include <hip/hip_runtime.h>

typedef _Float16 f16;
typedef _Float16 f16x8 __attribute__((ext_vector_type(8)));
typedef float    f32x4 __attribute__((ext_vector_type(4)));
typedef unsigned int uint32;

#define DEVI static __device__ __forceinline__

constexpr int BATCH = 64;
constexpr int TT    = 400;
constexpr int DIN   = 1024;    // layer input width (== 2*HH)
constexpr int HH    = 512;
constexpr int M6    = 6*HH;    // 3072: 6 gates, one direction
constexpr int NN    = 2*M6;    // 6144: both directions (Wi row count per layer)
constexpr int MM    = BATCH*TT;
constexpr int TC    = 50;      // timesteps per chunk
constexpr int NCH   = TT/TC;   // 8 chunks
constexpr int HR    = TC+1;    // 51 h-ring slots
constexpr int MCH   = TC*BATCH;// 3200 rows per chunk sub-GEMM

DEVI float sigm(float x)   { return __fdividef(1.f, 1.f + __expf(-x)); }
DEVI float tanh_f(float x) { return 1.f - __fdividef(2.f, 1.f + __expf(2.f*x)); }

DEVI void g2lds16(const void* g, void* l) {
    __builtin_amdgcn_global_load_lds(
        (const __attribute__((address_space(1))) uint32*)g,
        (__attribute__((address_space(3))) uint32*)l, 16, 0, 0);
}

// ---------------- x: (B,T,D) f32 -> (T,B,D) f16 ----------------
__global__ __launch_bounds__(256) void cvt_x(const float* __restrict__ x, f16* __restrict__ xb) {
    int g  = blockIdx.x*256 + threadIdx.x;   // over MM*DIN/4
    int d4 = g & 255;                        // DIN/4 = 256
    int bt = g >> 8;
    int b  = bt / TT, t = bt - b*TT;
    float4 v = *reinterpret_cast<const float4*>(x + (size_t)bt*DIN + d4*4);
    union { f16 h[4]; uint2 u; } pk;
    pk.h[0]=(f16)v.x; pk.h[1]=(f16)v.y; pk.h[2]=(f16)v.z; pk.h[3]=(f16)v.w;
    *reinterpret_cast<uint2*>(xb + (size_t)(t*BATCH + b)*DIN + d4*4) = pk.u;
}

// ---------------- generic f32 -> f16 ----------------
__global__ __launch_bounds__(256) void cvt_w(const float* __restrict__ s, f16* __restrict__ d, int n4) {
    int g = blockIdx.x*256 + threadIdx.x;
    if (g >= n4) return;
    float4 v = *reinterpret_cast<const float4*>(s + (size_t)g*4);
    union { f16 h[4]; uint2 u; } pk;
    pk.h[0]=(f16)v.x; pk.h[1]=(f16)v.y; pk.h[2]=(f16)v.z; pk.h[3]=(f16)v.w;
    *reinterpret_cast<uint2*>(d + (size_t)g*4) = pk.u;
}

// ---------------- chunk GEMM: C[m,n] = sum_k A[amap(m),k]*Bt[n,k] ----------------
// amap(m) = arow0 + (m>>6)*astep + (m&63)  (time-skewed row gather; astep = +-64)
// A rows f16 K-major, Bt: N x K row-major, C: M x N f16. M=3200, N=3072, K=1024.
__global__ __launch_bounds__(256) void gemm_nt(const f16* __restrict__ A, const f16* __restrict__ Bt,
                                               f16* __restrict__ C, int M, int N, int K,
                                               int arow0, int astep) {
    __shared__ f16 As[128*64];
    __shared__ f16 Bs[128*64];
    const int nbm = M >> 7;                 // 25
    const int GM  = 8;                      // bn-group for L2 reuse (N/128 = 24 divisible by 8)
    int g   = blockIdx.x;
    int bpg = GM * nbm;
    int grp = g / bpg, r = g - grp*bpg;
    int bn  = grp*GM + (r & (GM-1));
    int bm  = r >> 3;
    const int tid  = threadIdx.x;
    const int lane = tid & 63;
    const int w    = tid >> 6;
    const int wm   = w >> 1, wn = w & 1;

    f32x4 acc[4][4];
    #pragma unroll
    for (int i=0;i<4;i++)
        #pragma unroll
        for (int j=0;j<4;j++)
            acc[i][j] = f32x4{0.f,0.f,0.f,0.f};

    // per-thread A row (time-skewed gather), one of 4 staged row-groups each iter
    int arow[4];
    #pragma unroll
    for (int r4=0;r4<4;r4++) {
        int m = bm*128 + (tid>>3) + r4*32;
        arow[r4] = arow0 + (m>>6)*astep + (m&63);
    }
    const int kcol = (tid&7)*8;
    const f16* bptr = Bt + (size_t)(bn*128 + (tid>>3))*K + kcol;
    char* asb = (char*)As;
    char* bsb = (char*)Bs;

    for (int kt = 0; kt < K; kt += 64) {
        #pragma unroll
        for (int r4 = 0; r4 < 4; ++r4) {
            g2lds16(A + (size_t)arow[r4]*K + kt + kcol, asb + r4*4096 + w*1024);
            g2lds16(bptr + (size_t)r4*32*K + kt,        bsb + r4*4096 + w*1024);
        }
        __syncthreads();
        #pragma unroll
        for (int kk = 0; kk < 64; kk += 32) {
            f16x8 af[4], bf[4];
            const int kof = kk + (lane>>4)*8;
            #pragma unroll
            for (int i=0;i<4;i++)
                af[i] = *reinterpret_cast<const f16x8*>(&As[(wm*64 + i*16 + (lane&15))*64 + kof]);
            #pragma unroll
            for (int j=0;j<4;j++)
                bf[j] = *reinterpret_cast<const f16x8*>(&Bs[(wn*64 + j*16 + (lane&15))*64 + kof]);
            #pragma unroll
            for (int i=0;i<4;i++)
                #pragma unroll
                for (int j=0;j<4;j++)
                    acc[i][j] = __builtin_amdgcn_mfma_f32_16x16x32_f16(af[i], bf[j], acc[i][j], 0, 0, 0);
        }
        __syncthreads();
    }
    #pragma unroll
    for (int i=0;i<4;i++) {
        #pragma unroll
        for (int j=0;j<4;j++) {
            int row0 = bm*128 + wm*64 + i*16 + (lane>>4)*4;
            int col  = bn*128 + wn*64 + j*16 + (lane&15);
            #pragma unroll
            for (int q=0;q<4;q++)
                C[(size_t)(row0+q)*N + col] = (f16)acc[i][j][q];
        }
    }
}

// ---------------- persistent bidirectional LSTM scan, one 50-step chunk ----------------
// 64 WGs x 256 thr. WGs 0..31 forward, 32..63 backward; each WG owns 16 h-columns
// with its Ws slice resident in LDS (XOR-swizzled). Per-step cross-WG sync via 32
// producer flags; release fence -> flag store; consumer polls then acquire fence.
// h in a 51-slot ring (WG skew bounded to 1 step by the flag wait); c carried in cbuf.
__global__ __launch_bounds__(256) void lstm_scan(
    const f16* __restrict__ piF,   // [TC*B][M6] fwd pi chunk
    const f16* __restrict__ piB,   // [TC*B][M6] bwd pi chunk
    const f16* __restrict__ Wsl,   // [2][5*HH][HH] this layer
    const float* __restrict__ bsl, // [2][5*HH] this layer
    const int* __restrict__ lens,  // [B]
    f16* __restrict__ hring,       // [2][HR][B][HH]
    int* __restrict__ flags,       // [2][TT][32] this layer (pre-zeroed)
    f16* __restrict__ y16,         // layer0 out: (T,B,2H) f16
    float* __restrict__ y32,       // layer1 out: d_out seq (B,T,2H) f32
    float* __restrict__ cbuf,      // [2][B][HH] f32 c-state carry
    int s0, int first, int last)
{
    __shared__ f16 wlds[80*512];   // 80 KB: rows rr = gate*16 + jcol, swizzled
    const int tid  = threadIdx.x;
    const int lane = tid & 63;
    const int w    = tid >> 6;
    const int dir  = blockIdx.x >> 5;
    const int wgd  = blockIdx.x & 31;
    const int j0   = wgd*16;
    const int jl   = lane & 15;
    const int rq   = lane >> 4;

    // stage Ws slice into LDS with XOR swizzle (byte ^= (row&7)<<4)
    {
        const f16* wbase = Wsl + (size_t)dir*5*HH*HH;
        for (int c = tid; c < 80*64; c += 256) {      // 16B chunks, 64 per row
            int rr = c >> 6, cc = c & 63;
            int grow = (rr>>4)*HH + j0 + (rr&15);     // gate*512 + j0 + jcol
            uint4 v = *reinterpret_cast<const uint4*>(wbase + (size_t)grow*HH + cc*8);
            *reinterpret_cast<uint4*>((char*)wlds + rr*1024 + ((cc*16) ^ ((rr&7)<<4))) = v;
        }
    }

    int   lenr[4];
    float bias[5];
    #pragma unroll
    for (int r2=0;r2<4;r2++) lenr[r2] = lens[w*16 + rq*4 + r2];
    #pragma unroll
    for (int g2=0;g2<5;g2++) bias[g2] = bsl[dir*5*HH + g2*HH + j0 + jl];

    f16* hD  = hring + (size_t)dir*HR*BATCH*HH;
    int* flD = flags + dir*TT*32;
    const f16* piD = dir ? piB : piF;

    float cst[4];
    #pragma unroll
    for (int r2=0;r2<4;r2++) {
        int b = w*16 + rq*4 + r2;
        cst[r2] = first ? 0.f : cbuf[dir*BATCH*HH + b*HH + j0 + jl];
    }

    __syncthreads();

    for (int ts = s0; ts < s0 + TC; ++ts) {
        const int tau = dir ? (TT-1-ts) : ts;

        // pi prefetch (independent of cross-WG sync)
        const f16* pib = piD + (size_t)(ts - s0)*BATCH*M6 + j0 + jl;
        f16 praw[4][6];
        #pragma unroll
        for (int r2=0;r2<4;r2++) {
            int b = w*16 + rq*4 + r2;
            #pragma unroll
            for (int g2=0;g2<6;g2++)
                praw[r2][g2] = pib[(size_t)b*M6 + g2*HH];
        }

        // wait for all 32 producers of step ts-1 (within this chunk)
        if (ts > s0) {
            if (w == 0) {
                int* fl = flD + (ts-1)*32;
                long iters = 0;
                for (;;) {
                    int v = (lane < 32) ? __hip_atomic_load(fl + lane, __ATOMIC_RELAXED, __HIP_MEMORY_SCOPE_AGENT) : 1;
                    if (__all(v != 0)) break;
                    __builtin_amdgcn_s_sleep(2);
                    if (++iters > 5000000L) break;   // fail visibly instead of hanging
                }
                __builtin_amdgcn_fence(__ATOMIC_ACQUIRE, "agent");
            }
            __syncthreads();
        }

        const f16* ht = hD + (size_t)(ts % HR)*BATCH*HH;
        // A-fragments of h straight into VGPRs (16 x 16B per lane)
        f16x8 af[16];
        {
            const f16* hb = ht + (size_t)(w*16 + jl)*HH + rq*8;
            #pragma unroll
            for (int ks=0; ks<16; ++ks)
                af[ks] = *reinterpret_cast<const f16x8*>(hb + ks*32);
        }
        f16 hold[4];
        #pragma unroll
        for (int r2=0;r2<4;r2++)
            hold[r2] = ht[(size_t)(w*16 + rq*4 + r2)*HH + j0 + jl];

        // ps = h @ Ws_slice^T : 5 gates x 16 K-steps of 16x16x32 MFMA
        f32x4 accP[5];
        #pragma unroll
        for (int g2=0;g2<5;g2++) accP[g2] = f32x4{0.f,0.f,0.f,0.f};
        #pragma unroll
        for (int ks=0; ks<16; ++ks) {
            const int kbyte = ks*64 + rq*16;
            #pragma unroll
            for (int g2=0; g2<5; ++g2) {
                const int rr = g2*16 + jl;
                f16x8 bfr = *reinterpret_cast<const f16x8*>((char*)wlds + rr*1024 + (kbyte ^ ((rr&7)<<4)));
                accP[g2] = __builtin_amdgcn_mfma_f32_16x16x32_f16(af[ks], bfr, accP[g2], 0, 0, 0);
            }
        }

        // gates (fp32), highway, masking
        f16   hnew[4];
        float yv[4];
        #pragma unroll
        for (int r2=0;r2<4;r2++) {
            float ig = sigm  (accP[0][r2] + (float)praw[r2][0] + bias[0]);
            float fg = sigm  (accP[1][r2] + (float)praw[r2][1] + bias[1]);
            float mg = tanh_f(accP[2][r2] + (float)praw[r2][2] + bias[2]);
            float og = sigm  (accP[3][r2] + (float)praw[r2][3] + bias[3]);
            float hw = sigm  (accP[4][r2] + (float)praw[r2][4] + bias[4]);
            float cn = ig*mg + fg*cst[r2];
            float op = og * tanh_f(cn);
            float ov = hw*op + (1.f - hw)*(float)praw[r2][5];
            bool act = (tau < lenr[r2]);
            float h2 = act ? ov : (float)hold[r2];
            cst[r2]  = act ? cn : cst[r2];
            yv[r2]   = act ? ov : 0.f;
            hnew[r2] = (f16)h2;
        }

        // publish h[ts+1] (ring), then signal
        {
            f16* hn = hD + (size_t)((ts+1) % HR)*BATCH*HH;
            #pragma unroll
            for (int r2=0;r2<4;r2++)
                hn[(size_t)(w*16 + rq*4 + r2)*HH + j0 + jl] = hnew[r2];
        }
        __builtin_amdgcn_fence(__ATOMIC_RELEASE, "agent");
        __syncthreads();
        if (tid == 0)
            __hip_atomic_store(flD + ts*32 + wgd, 1, __ATOMIC_RELAXED, __HIP_MEMORY_SCOPE_AGENT);

        // y writes off the critical path
        if (!last) {
            #pragma unroll
            for (int r2=0;r2<4;r2++) {
                int b = w*16 + rq*4 + r2;
                y16[(size_t)(tau*BATCH + b)*DIN + dir*HH + j0 + jl] = (f16)yv[r2];
            }
        } else {
            #pragma unroll
            for (int r2=0;r2<4;r2++) {
                int b = w*16 + rq*4 + r2;
                y32[(size_t)(b*TT + tau)*DIN + dir*HH + j0 + jl] = yv[r2];
            }
        }
    }

    // carry c-state to next chunk (exclusive (dir, b, j) ownership per lane)
    #pragma unroll
    for (int r2=0;r2<4;r2++) {
        int b = w*16 + rq*4 + r2;
        cbuf[dir*BATCH*HH + b*HH + j0 + jl] = cst[r2];
    }
}

// ---------------- finalize: h[T] (ring slot), c -> d_out (B,2H) f32 ----------------
__global__ __launch_bounds__(256) void finalize(const f16* __restrict__ hring,
                                                const float* __restrict__ cbuf,
                                                float* __restrict__ outh,
                                                float* __restrict__ outc, int slot) {
    int i = blockIdx.x*256 + threadIdx.x;        // 0..65535 = dir*32768 + b*512 + j
    int dir = i >> 15, rem = i & 32767;
    int b = rem >> 9, j = rem & 511;
    outh[(size_t)b*(2*HH) + dir*HH + j] =
        (float)hring[(size_t)dir*HR*BATCH*HH + (size_t)slot*BATCH*HH + (size_t)b*HH + j];
    outc[(size_t)b*(2*HH) + dir*HH + j] = cbuf[dir*BATCH*HH + b*HH + j];
}

extern "C" void kernel_launch(void* const* d_in, const int* in_sizes, int n_in,
                              void* d_out, int out_size, void* d_ws, size_t ws_size,
                              hipStream_t stream) {
    (void)in_sizes; (void)n_in; (void)out_size; (void)ws_size;
    const float* x    = (const float*)d_in[0];
    const int*   lens = (const int*)  d_in[1];
    const float* Wi   = (const float*)d_in[2];
    const float* Ws   = (const float*)d_in[3];
    const float* bs   = (const float*)d_in[4];
    float* out = (float*)d_out;

    char* ws = (char*)d_ws;
    size_t off = 0;
    auto alloc = [&](size_t bytes) -> char* {
        char* p = ws + off;
        off += (bytes + 1023) & ~(size_t)1023;
        return p;
    };
    f16* xb0   = (f16*)alloc((size_t)MM*DIN*2);        // 52.4 MB  layer-0 input (T,B,D) f16
    f16* xb1   = (f16*)alloc((size_t)MM*DIN*2);        // 52.4 MB  layer-0 output / layer-1 input
    f16* wi16  = (f16*)alloc((size_t)NN*DIN*2);        // 12.6 MB  current layer Wi f16
    f16* ws16  = (f16*)alloc((size_t)2*2*5*HH*HH*2);   // 10.5 MB  all Ws f16
    f16* piF   = (f16*)alloc((size_t)MCH*M6*2);        // 19.7 MB  fwd pi chunk
    f16* piB   = (f16*)alloc((size_t)MCH*M6*2);        // 19.7 MB  bwd pi chunk
    f16* hring = (f16*)alloc((size_t)2*HR*BATCH*HH*2); //  6.7 MB  h ring
    float* cbuf= (float*)alloc((size_t)2*BATCH*HH*4);  //  0.3 MB  c carry
    int* flags = (int*)alloc((size_t)2*2*TT*32*4);     //  0.4 MB
    // total ~175 MB

    (void)hipMemsetAsync(flags, 0, (size_t)2*2*TT*32*4, stream);
    (void)hipMemsetAsync(hring, 0, (size_t)BATCH*HH*2, stream);                               // dir0 slot0 = h[0]
    (void)hipMemsetAsync((char*)hring + (size_t)HR*BATCH*HH*2, 0, (size_t)BATCH*HH*2, stream);// dir1 slot0

    cvt_x<<<MM*DIN/4/256, 256, 0, stream>>>(x, xb0);
    cvt_w<<<(2*2*5*HH*HH/4)/256, 256, 0, stream>>>(Ws, ws16, 2*2*5*HH*HH/4);

    float* outh = out + (size_t)MM*DIN;           // seq is (B,T,2H)
    float* outc = outh + (size_t)2*BATCH*2*HH;    // after final_h (L,B,2H)

    for (int layer = 0; layer < 2; ++layer) {
        if (layer == 1) {  // re-zero h[0] ring slots (clobbered by ring wrap in layer 0)
            (void)hipMemsetAsync(hring, 0, (size_t)BATCH*HH*2, stream);
            (void)hipMemsetAsync((char*)hring + (size_t)HR*BATCH*HH*2, 0, (size_t)BATCH*HH*2, stream);
        }
        cvt_w<<<(NN*DIN/4)/256, 256, 0, stream>>>(Wi + (size_t)layer*NN*DIN, wi16, NN*DIN/4);
        const f16* Axb = layer ? xb1 : xb0;
        for (int k = 0; k < NCH; ++k) {
            int s0 = k*TC;
            gemm_nt<<<(MCH/128)*(M6/128), 256, 0, stream>>>(Axb, wi16,                 piF, MCH, M6, DIN, s0*64, 64);
            gemm_nt<<<(MCH/128)*(M6/128), 256, 0, stream>>>(Axb, wi16 + (size_t)M6*DIN, piB, MCH, M6, DIN, (TT-1-s0)*64, -64);
            lstm_scan<<<64, 256, 0, stream>>>(piF, piB,
                ws16 + (size_t)layer*2*5*HH*HH,
                bs   + (size_t)layer*2*5*HH,
                lens, hring,
                flags + (size_t)layer*2*TT*32,
                xb1, out, cbuf, s0, k==0, layer);
        }
        finalize<<<(2*BATCH*HH)/256, 256, 0, stream>>>(hring, cbuf,
            outh + (size_t)layer*BATCH*2*HH,
            outc + (size_t)layer*BATCH*2*HH, TT % HR);
    }
}

// Round 3
// 6598.161 us; speedup vs baseline: 1.5680x; 1.5680x over previous
//
#include <hip/hip_runtime.h>

typedef _Float16 f16;
typedef _Float16 f16x8 __attribute__((ext_vector_type(8)));
typedef float    f32x4 __attribute__((ext_vector_type(4)));
typedef unsigned int uint32;

#define DEVI static __device__ __forceinline__

constexpr int BATCH = 64;
constexpr int TT    = 400;
constexpr int DIN   = 1024;    // layer input width (== 2*HH)
constexpr int HH    = 512;
constexpr int M6    = 6*HH;    // 3072: 6 gates, one direction
constexpr int NN    = 2*M6;    // 6144: both directions (Wi row count per layer)
constexpr int MM    = BATCH*TT;
constexpr int TC    = 50;      // timesteps per chunk
constexpr int NCH   = TT/TC;   // 8 chunks
constexpr int HR    = TC+1;    // 51 h-ring slots
constexpr int MCH   = TC*BATCH;// 3200 rows per chunk sub-GEMM

DEVI float sigm(float x)   { return __fdividef(1.f, 1.f + __expf(-x)); }
DEVI float tanh_f(float x) { return 1.f - __fdividef(2.f, 1.f + __expf(2.f*x)); }

DEVI void g2lds16(const void* g, void* l) {
    __builtin_amdgcn_global_load_lds(
        (const __attribute__((address_space(1))) uint32*)g,
        (__attribute__((address_space(3))) uint32*)l, 16, 0, 0);
}

// ---- coherent (LLC-level, cross-XCD) accesses: bypass L1+L2 via sc0 sc1 ----
DEVI f16x8 ldgc_b128(const f16* p) {
    f16x8 r;
    asm volatile("global_load_dwordx4 %0, %1, off sc0 sc1"
                 : "=v"(r) : "v"(p) : "memory");
    return r;   // NOT valid until waitv0()
}
DEVI unsigned int ldgc_u16(const f16* p) {
    unsigned int r;
    asm volatile("global_load_ushort %0, %1, off sc0 sc1"
                 : "=v"(r) : "v"(p) : "memory");
    return r;   // NOT valid until waitv0()
}
DEVI void stgc_u16(f16* p, unsigned short v) {
    unsigned int vv = v;
    asm volatile("global_store_short %1, %0, off sc0 sc1"
                 :: "v"(vv), "v"(p) : "memory");
}
DEVI void waitv0() {
    asm volatile("s_waitcnt vmcnt(0)" ::: "memory");
    __builtin_amdgcn_sched_barrier(0);   // rule #18: stop MFMA/VALU hoisting past the wait
}

// ---------------- x: (B,T,D) f32 -> (T,B,D) f16 ----------------
__global__ __launch_bounds__(256) void cvt_x(const float* __restrict__ x, f16* __restrict__ xb) {
    int g  = blockIdx.x*256 + threadIdx.x;   // over MM*DIN/4
    int d4 = g & 255;                        // DIN/4 = 256
    int bt = g >> 8;
    int b  = bt / TT, t = bt - b*TT;
    float4 v = *reinterpret_cast<const float4*>(x + (size_t)bt*DIN + d4*4);
    union { f16 h[4]; uint2 u; } pk;
    pk.h[0]=(f16)v.x; pk.h[1]=(f16)v.y; pk.h[2]=(f16)v.z; pk.h[3]=(f16)v.w;
    *reinterpret_cast<uint2*>(xb + (size_t)(t*BATCH + b)*DIN + d4*4) = pk.u;
}

// ---------------- generic f32 -> f16 ----------------
__global__ __launch_bounds__(256) void cvt_w(const float* __restrict__ s, f16* __restrict__ d, int n4) {
    int g = blockIdx.x*256 + threadIdx.x;
    if (g >= n4) return;
    float4 v = *reinterpret_cast<const float4*>(s + (size_t)g*4);
    union { f16 h[4]; uint2 u; } pk;
    pk.h[0]=(f16)v.x; pk.h[1]=(f16)v.y; pk.h[2]=(f16)v.z; pk.h[3]=(f16)v.w;
    *reinterpret_cast<uint2*>(d + (size_t)g*4) = pk.u;
}

// ---------------- chunk GEMM: C[m,n] = sum_k A[amap(m),k]*Bt[n,k] ----------------
// amap(m) = arow0 + (m>>6)*astep + (m&63)  (time-skewed row gather; astep = +-64)
__global__ __launch_bounds__(256) void gemm_nt(const f16* __restrict__ A, const f16* __restrict__ Bt,
                                               f16* __restrict__ C, int M, int N, int K,
                                               int arow0, int astep) {
    __shared__ f16 As[128*64];
    __shared__ f16 Bs[128*64];
    const int nbm = M >> 7;                 // 25
    const int GM  = 8;                      // bn-group for L2 reuse (N/128 = 24 divisible by 8)
    int g   = blockIdx.x;
    int bpg = GM * nbm;
    int grp = g / bpg, r = g - grp*bpg;
    int bn  = grp*GM + (r & (GM-1));
    int bm  = r >> 3;
    const int tid  = threadIdx.x;
    const int lane = tid & 63;
    const int w    = tid >> 6;
    const int wm   = w >> 1, wn = w & 1;

    f32x4 acc[4][4];
    #pragma unroll
    for (int i=0;i<4;i++)
        #pragma unroll
        for (int j=0;j<4;j++)
            acc[i][j] = f32x4{0.f,0.f,0.f,0.f};

    int arow[4];
    #pragma unroll
    for (int r4=0;r4<4;r4++) {
        int m = bm*128 + (tid>>3) + r4*32;
        arow[r4] = arow0 + (m>>6)*astep + (m&63);
    }
    const int kcol = (tid&7)*8;
    const f16* bptr = Bt + (size_t)(bn*128 + (tid>>3))*K + kcol;
    char* asb = (char*)As;
    char* bsb = (char*)Bs;

    for (int kt = 0; kt < K; kt += 64) {
        #pragma unroll
        for (int r4 = 0; r4 < 4; ++r4) {
            g2lds16(A + (size_t)arow[r4]*K + kt + kcol, asb + r4*4096 + w*1024);
            g2lds16(bptr + (size_t)r4*32*K + kt,        bsb + r4*4096 + w*1024);
        }
        __syncthreads();
        #pragma unroll
        for (int kk = 0; kk < 64; kk += 32) {
            f16x8 af[4], bf[4];
            const int kof = kk + (lane>>4)*8;
            #pragma unroll
            for (int i=0;i<4;i++)
                af[i] = *reinterpret_cast<const f16x8*>(&As[(wm*64 + i*16 + (lane&15))*64 + kof]);
            #pragma unroll
            for (int j=0;j<4;j++)
                bf[j] = *reinterpret_cast<const f16x8*>(&Bs[(wn*64 + j*16 + (lane&15))*64 + kof]);
            #pragma unroll
            for (int i=0;i<4;i++)
                #pragma unroll
                for (int j=0;j<4;j++)
                    acc[i][j] = __builtin_amdgcn_mfma_f32_16x16x32_f16(af[i], bf[j], acc[i][j], 0, 0, 0);
        }
        __syncthreads();
    }
    #pragma unroll
    for (int i=0;i<4;i++) {
        #pragma unroll
        for (int j=0;j<4;j++) {
            int row0 = bm*128 + wm*64 + i*16 + (lane>>4)*4;
            int col  = bn*128 + wn*64 + j*16 + (lane&15);
            #pragma unroll
            for (int q=0;q<4;q++)
                C[(size_t)(row0+q)*N + col] = (f16)acc[i][j][q];
        }
    }
}

// ---------------- persistent bidirectional LSTM scan, one 50-step chunk ----------------
// 64 WGs x 256 thr. WGs 0..31 forward, 32..63 backward; each WG owns 16 h-columns with
// its Ws slice resident in LDS (XOR-swizzled). Per-step cross-WG sync via 32 producer
// flags. NO cache-granular fences: h traffic is element-coherent (sc0 sc1 asm ops),
// ordering via explicit s_waitcnt vmcnt(0) before the relaxed flag store / after poll.
__global__ __launch_bounds__(256) void lstm_scan(
    const f16* __restrict__ piF,   // [TC*B][M6] fwd pi chunk
    const f16* __restrict__ piB,   // [TC*B][M6] bwd pi chunk
    const f16* __restrict__ Wsl,   // [2][5*HH][HH] this layer
    const float* __restrict__ bsl, // [2][5*HH] this layer
    const int* __restrict__ lens,  // [B]
    f16* __restrict__ hring,       // [2][HR][B][HH]
    int* __restrict__ flags,       // [2][TT][32] this layer (pre-zeroed)
    f16* __restrict__ y16,         // layer0 out: (T,B,2H) f16
    float* __restrict__ y32,       // layer1 out: d_out seq (B,T,2H) f32
    float* __restrict__ cbuf,      // [2][B][HH] f32 c-state carry
    int s0, int first, int last)
{
    __shared__ f16 wlds[80*512];   // 80 KB: rows rr = gate*16 + jcol, swizzled
    const int tid  = threadIdx.x;
    const int lane = tid & 63;
    const int w    = tid >> 6;
    const int dir  = blockIdx.x >> 5;
    const int wgd  = blockIdx.x & 31;
    const int j0   = wgd*16;
    const int jl   = lane & 15;
    const int rq   = lane >> 4;

    // stage Ws slice into LDS with XOR swizzle (byte ^= (row&7)<<4)
    {
        const f16* wbase = Wsl + (size_t)dir*5*HH*HH;
        for (int c = tid; c < 80*64; c += 256) {      // 16B chunks, 64 per row
            int rr = c >> 6, cc = c & 63;
            int grow = (rr>>4)*HH + j0 + (rr&15);     // gate*512 + j0 + jcol
            uint4 v = *reinterpret_cast<const uint4*>(wbase + (size_t)grow*HH + cc*8);
            *reinterpret_cast<uint4*>((char*)wlds + rr*1024 + ((cc*16) ^ ((rr&7)<<4))) = v;
        }
    }

    int   lenr[4];
    float bias[5];
    #pragma unroll
    for (int r2=0;r2<4;r2++) lenr[r2] = lens[w*16 + rq*4 + r2];
    #pragma unroll
    for (int g2=0;g2<5;g2++) bias[g2] = bsl[dir*5*HH + g2*HH + j0 + jl];

    f16* hD  = hring + (size_t)dir*HR*BATCH*HH;
    int* flD = flags + dir*TT*32;
    const f16* piD = dir ? piB : piF;

    float cst[4];
    #pragma unroll
    for (int r2=0;r2<4;r2++) {
        int b = w*16 + rq*4 + r2;
        cst[r2] = first ? 0.f : cbuf[dir*BATCH*HH + b*HH + j0 + jl];
    }

    __syncthreads();

    for (int ts = s0; ts < s0 + TC; ++ts) {
        const int tau = dir ? (TT-1-ts) : ts;

        // pi prefetch (normal cached loads; stays cached — no more buffer_inv)
        const f16* pib = piD + (size_t)(ts - s0)*BATCH*M6 + j0 + jl;
        f16 praw[4][6];
        #pragma unroll
        for (int r2=0;r2<4;r2++) {
            int b = w*16 + rq*4 + r2;
            #pragma unroll
            for (int g2=0;g2<6;g2++)
                praw[r2][g2] = pib[(size_t)b*M6 + g2*HH];
        }

        // wait for all 32 producers of step ts-1 (within this chunk)
        if (ts > s0) {
            if (w == 0) {
                int* fl = flD + (ts-1)*32;
                long iters = 0;
                for (;;) {
                    int v = (lane < 32) ? __hip_atomic_load(fl + lane, __ATOMIC_RELAXED, __HIP_MEMORY_SCOPE_AGENT) : 1;
                    if (__all(v != 0)) break;
                    __builtin_amdgcn_s_sleep(1);
                    if (++iters > 5000000L) break;   // fail visibly instead of hanging
                }
            }
            __syncthreads();
        }

        const f16* ht = hD + (size_t)(ts % HR)*BATCH*HH;
        // coherent h loads: A-fragments straight into VGPRs (16 x 16B per lane)
        f16x8 af[16];
        {
            const f16* hb = ht + (size_t)(w*16 + jl)*HH + rq*8;
            #pragma unroll
            for (int ks=0; ks<16; ++ks)
                af[ks] = ldgc_b128(hb + ks*32);
        }
        unsigned int holdb[4];
        #pragma unroll
        for (int r2=0;r2<4;r2++)
            holdb[r2] = ldgc_u16(ht + (size_t)(w*16 + rq*4 + r2)*HH + j0 + jl);
        waitv0();   // af/hold now valid

        // ps = h @ Ws_slice^T : 5 gates x 16 K-steps of 16x16x32 MFMA
        f32x4 accP[5];
        #pragma unroll
        for (int g2=0;g2<5;g2++) accP[g2] = f32x4{0.f,0.f,0.f,0.f};
        #pragma unroll
        for (int ks=0; ks<16; ++ks) {
            const int kbyte = ks*64 + rq*16;
            #pragma unroll
            for (int g2=0; g2<5; ++g2) {
                const int rr = g2*16 + jl;
                f16x8 bfr = *reinterpret_cast<const f16x8*>((char*)wlds + rr*1024 + (kbyte ^ ((rr&7)<<4)));
                accP[g2] = __builtin_amdgcn_mfma_f32_16x16x32_f16(af[ks], bfr, accP[g2], 0, 0, 0);
            }
        }

        // gates (fp32), highway, masking
        unsigned short hnewb[4];
        float yv[4];
        #pragma unroll
        for (int r2=0;r2<4;r2++) {
            float ig = sigm  (accP[0][r2] + (float)praw[r2][0] + bias[0]);
            float fg = sigm  (accP[1][r2] + (float)praw[r2][1] + bias[1]);
            float mg = tanh_f(accP[2][r2] + (float)praw[r2][2] + bias[2]);
            float og = sigm  (accP[3][r2] + (float)praw[r2][3] + bias[3]);
            float hw = sigm  (accP[4][r2] + (float)praw[r2][4] + bias[4]);
            float cn = ig*mg + fg*cst[r2];
            float op = og * tanh_f(cn);
            float ov = hw*op + (1.f - hw)*(float)praw[r2][5];
            bool act = (tau < lenr[r2]);
            union { unsigned short u; f16 h; } hv; hv.u = (unsigned short)holdb[r2];
            float h2 = act ? ov : (float)hv.h;
            cst[r2]  = act ? cn : cst[r2];
            yv[r2]   = act ? ov : 0.f;
            union { unsigned short u; f16 h; } nv; nv.h = (f16)h2;
            hnewb[r2] = nv.u;
        }

        // publish h[ts+1] (ring) coherently, drain, then signal
        {
            f16* hn = hD + (size_t)((ts+1) % HR)*BATCH*HH;
            #pragma unroll
            for (int r2=0;r2<4;r2++)
                stgc_u16(hn + (size_t)(w*16 + rq*4 + r2)*HH + j0 + jl, hnewb[r2]);
        }
        waitv0();        // all h stores at LLC
        __syncthreads(); // all 4 waves drained
        if (tid == 0)
            __hip_atomic_store(flD + ts*32 + wgd, 1, __ATOMIC_RELAXED, __HIP_MEMORY_SCOPE_AGENT);

        // y writes off the critical path (normal cached stores)
        if (!last) {
            #pragma unroll
            for (int r2=0;r2<4;r2++) {
                int b = w*16 + rq*4 + r2;
                y16[(size_t)(tau*BATCH + b)*DIN + dir*HH + j0 + jl] = (f16)yv[r2];
            }
        } else {
            #pragma unroll
            for (int r2=0;r2<4;r2++) {
                int b = w*16 + rq*4 + r2;
                y32[(size_t)(b*TT + tau)*DIN + dir*HH + j0 + jl] = yv[r2];
            }
        }
    }

    // carry c-state to next chunk (exclusive (dir, b, j) ownership per lane)
    #pragma unroll
    for (int r2=0;r2<4;r2++) {
        int b = w*16 + rq*4 + r2;
        cbuf[dir*BATCH*HH + b*HH + j0 + jl] = cst[r2];
    }
}

// ---------------- finalize: h[T] (ring slot), c -> d_out (B,2H) f32 ----------------
__global__ __launch_bounds__(256) void finalize(const f16* __restrict__ hring,
                                                const float* __restrict__ cbuf,
                                                float* __restrict__ outh,
                                                float* __restrict__ outc, int slot) {
    int i = blockIdx.x*256 + threadIdx.x;        // 0..65535 = dir*32768 + b*512 + j
    int dir = i >> 15, rem = i & 32767;
    int b = rem >> 9, j = rem & 511;
    outh[(size_t)b*(2*HH) + dir*HH + j] =
        (float)hring[(size_t)dir*HR*BATCH*HH + (size_t)slot*BATCH*HH + (size_t)b*HH + j];
    outc[(size_t)b*(2*HH) + dir*HH + j] = cbuf[dir*BATCH*HH + b*HH + j];
}

extern "C" void kernel_launch(void* const* d_in, const int* in_sizes, int n_in,
                              void* d_out, int out_size, void* d_ws, size_t ws_size,
                              hipStream_t stream) {
    (void)in_sizes; (void)n_in; (void)out_size; (void)ws_size;
    const float* x    = (const float*)d_in[0];
    const int*   lens = (const int*)  d_in[1];
    const float* Wi   = (const float*)d_in[2];
    const float* Ws   = (const float*)d_in[3];
    const float* bs   = (const float*)d_in[4];
    float* out = (float*)d_out;

    char* ws = (char*)d_ws;
    size_t off = 0;
    auto alloc = [&](size_t bytes) -> char* {
        char* p = ws + off;
        off += (bytes + 1023) & ~(size_t)1023;
        return p;
    };
    f16* xb0   = (f16*)alloc((size_t)MM*DIN*2);        // 52.4 MB  layer-0 input (T,B,D) f16
    f16* xb1   = (f16*)alloc((size_t)MM*DIN*2);        // 52.4 MB  layer-0 output / layer-1 input
    f16* wi16  = (f16*)alloc((size_t)NN*DIN*2);        // 12.6 MB  current layer Wi f16
    f16* ws16  = (f16*)alloc((size_t)2*2*5*HH*HH*2);   // 10.5 MB  all Ws f16
    f16* piF   = (f16*)alloc((size_t)MCH*M6*2);        // 19.7 MB  fwd pi chunk
    f16* piB   = (f16*)alloc((size_t)MCH*M6*2);        // 19.7 MB  bwd pi chunk
    f16* hring = (f16*)alloc((size_t)2*HR*BATCH*HH*2); //  6.7 MB  h ring
    float* cbuf= (float*)alloc((size_t)2*BATCH*HH*4);  //  0.3 MB  c carry
    int* flags = (int*)alloc((size_t)2*2*TT*32*4);     //  0.4 MB
    // total ~175 MB

    (void)hipMemsetAsync(flags, 0, (size_t)2*2*TT*32*4, stream);
    (void)hipMemsetAsync(hring, 0, (size_t)BATCH*HH*2, stream);                               // dir0 slot0 = h[0]
    (void)hipMemsetAsync((char*)hring + (size_t)HR*BATCH*HH*2, 0, (size_t)BATCH*HH*2, stream);// dir1 slot0

    cvt_x<<<MM*DIN/4/256, 256, 0, stream>>>(x, xb0);
    cvt_w<<<(2*2*5*HH*HH/4)/256, 256, 0, stream>>>(Ws, ws16, 2*2*5*HH*HH/4);

    float* outh = out + (size_t)MM*DIN;           // seq is (B,T,2H)
    float* outc = outh + (size_t)2*BATCH*2*HH;    // after final_h (L,B,2H)

    for (int layer = 0; layer < 2; ++layer) {
        if (layer == 1) {  // re-zero h[0] ring slots (clobbered by ring wrap in layer 0)
            (void)hipMemsetAsync(hring, 0, (size_t)BATCH*HH*2, stream);
            (void)hipMemsetAsync((char*)hring + (size_t)HR*BATCH*HH*2, 0, (size_t)BATCH*HH*2, stream);
        }
        cvt_w<<<(NN*DIN/4)/256, 256, 0, stream>>>(Wi + (size_t)layer*NN*DIN, wi16, NN*DIN/4);
        const f16* Axb = layer ? xb1 : xb0;
        for (int k = 0; k < NCH; ++k) {
            int s0 = k*TC;
            gemm_nt<<<(MCH/128)*(M6/128), 256, 0, stream>>>(Axb, wi16,                 piF, MCH, M6, DIN, s0*64, 64);
            gemm_nt<<<(MCH/128)*(M6/128), 256, 0, stream>>>(Axb, wi16 + (size_t)M6*DIN, piB, MCH, M6, DIN, (TT-1-s0)*64, -64);
            lstm_scan<<<64, 256, 0, stream>>>(piF, piB,
                ws16 + (size_t)layer*2*5*HH*HH,
                bs   + (size_t)layer*2*5*HH,
                lens, hring,
                flags + (size_t)layer*2*TT*32,
                xb1, out, cbuf, s0, k==0, layer);
        }
        finalize<<<(2*BATCH*HH)/256, 256, 0, stream>>>(hring, cbuf,
            outh + (size_t)layer*BATCH*2*HH,
            outc + (size_t)layer*BATCH*2*HH, TT % HR);
    }
}